// Round 4
// baseline (416.519 us; speedup 1.0000x reference)
//
#include <hip/hip_runtime.h>

#define N_ROWS   1048576
#define T_COLS   32
#define NBLK     2048
#define BLOCK    256
#define ROWS_PER_BLK  (N_ROWS / NBLK)        // 512
#define ROWS_PER_GRP  (ROWS_PER_BLK / 8)     // 64 rows per thread
#define NWS      2080                         // 1024 Gt + 1024 Gp + 32 colsums

// R2's 8x8-tile mapping (8x L1 broadcast redundancy, half of R3's 16x),
// spill-proofed: single-row body (16 load regs) + unroll 2 keeps live set
// ~110 VGPRs, and amdgpu_waves_per_eu(4,4) pins the allocator at 4 waves/EU
// (128-VGPR budget) so it pipelines loads instead of chasing 8 waves with
// scratch spills (R2 failure) or 32-VGPR no-ILP serialization (R3 failure).
//   g   = tid>>5 : row-group, owns 64 contiguous rows
//   tau = tid&31 : mtx = tau>>4 (0=y_true,1=y_pred); tt=tau&15 -> 8x8 tile
__global__ __launch_bounds__(256, 4)
__attribute__((amdgpu_waves_per_eu(4, 4)))
void ts_gram(const float* __restrict__ y_pred,
             const float* __restrict__ y_true,
             float* __restrict__ ws) {
    __shared__ float s_red[NWS];

    const int tid = threadIdx.x;
    const int g   = tid >> 5;
    const int tau = tid & 31;
    const int mtx = tau >> 4;
    const int tt  = tau & 15;
    const int j0  = (tt >> 2) * 8;
    const int k0  = (tt & 3) * 8;
    const bool do_sum = (mtx == 0) & (k0 == 0);   // 4 lanes per half cover all j

    const float* src = mtx ? y_pred : y_true;
    const float* p = src + ((size_t)blockIdx.x * ROWS_PER_BLK + (size_t)g * ROWS_PER_GRP) * T_COLS;

    float acc[8][8];
    #pragma unroll
    for (int a = 0; a < 8; ++a)
        #pragma unroll
        for (int b = 0; b < 8; ++b) acc[a][b] = 0.0f;
    float sumv[8];
    #pragma unroll
    for (int a = 0; a < 8; ++a) sumv[a] = 0.0f;

    #pragma unroll 2
    for (int r = 0; r < ROWS_PER_GRP; ++r) {
        const float* row = p + r * T_COLS;
        float4 a0 = *(const float4*)(row + j0);
        float4 a1 = *(const float4*)(row + j0 + 4);
        float4 b0 = *(const float4*)(row + k0);
        float4 b1 = *(const float4*)(row + k0 + 4);
        float aj[8] = {a0.x, a0.y, a0.z, a0.w, a1.x, a1.y, a1.z, a1.w};
        float bk[8] = {b0.x, b0.y, b0.z, b0.w, b1.x, b1.y, b1.z, b1.w};
        #pragma unroll
        for (int jj = 0; jj < 8; ++jj)
            #pragma unroll
            for (int kk = 0; kk < 8; ++kk)
                acc[jj][kk] = fmaf(aj[jj], bk[kk], acc[jj][kk]);
        if (do_sum) {
            #pragma unroll
            for (int jj = 0; jj < 8; ++jj) sumv[jj] += aj[jj];
        }
    }

    // ---- block reduction: 8 row-groups collide per (tau,jj,kk) entry ----
    for (int i = tid; i < NWS; i += BLOCK) s_red[i] = 0.0f;
    __syncthreads();
    #pragma unroll
    for (int jj = 0; jj < 8; ++jj)
        #pragma unroll
        for (int kk = 0; kk < 8; ++kk)
            atomicAdd(&s_red[mtx * 1024 + (j0 + jj) * 32 + (k0 + kk)], acc[jj][kk]);
    if (do_sum) {
        #pragma unroll
        for (int jj = 0; jj < 8; ++jj) atomicAdd(&s_red[2048 + j0 + jj], sumv[jj]);
    }
    __syncthreads();
    for (int i = tid; i < NWS; i += BLOCK) atomicAdd(&ws[i], s_red[i]);
}

__global__ __launch_bounds__(1024) void ts_final(const float* __restrict__ w,
                                                 float* __restrict__ out) {
    __shared__ float s_S[32], s_nx[32], s_pn[32];
    __shared__ float s_red[16];
    const int tid = threadIdx.x;
    const float invN = 1.0f / (float)N_ROWS;

    if (tid < 32) {
        float S = w[2048 + tid];
        s_S[tid] = S;
        float d = w[tid * 32 + tid] - S * S * invN;   // centered diag
        s_nx[tid] = sqrtf(d);
        s_pn[tid] = sqrtf(w[1024 + tid * 33]);
    }
    __syncthreads();

    const int j = tid >> 5, k = tid & 31;
    float contrib = 0.0f;
    if (j >= 1 && k > j) {
        float gc  = w[j * 32 + k] - s_S[j] * s_S[k] * invN;
        float pcc = gc / (s_nx[j] * s_nx[k]);
        float cs  = w[1024 + j * 32 + k] / fmaxf(s_pn[j] * s_pn[k], 1e-8f);
        if (pcc >= 0.0f) contrib = 1.0f - cs;
    }
    #pragma unroll
    for (int off = 32; off > 0; off >>= 1) contrib += __shfl_down(contrib, off);
    if ((tid & 63) == 0) s_red[tid >> 6] = contrib;
    __syncthreads();
    if (tid == 0) {
        float tot = 0.0f;
        #pragma unroll
        for (int i = 0; i < 16; ++i) tot += s_red[i];
        out[0] = tot * (1.0f / 465.0f);   // c = (T-1)(T-2)/2
    }
}

extern "C" void kernel_launch(void* const* d_in, const int* in_sizes, int n_in,
                              void* d_out, int out_size, void* d_ws, size_t ws_size,
                              hipStream_t stream) {
    const float* y_pred = (const float*)d_in[0];
    const float* y_true = (const float*)d_in[1];
    float* out = (float*)d_out;
    float* ws  = (float*)d_ws;

    hipMemsetAsync(ws, 0, NWS * sizeof(float), stream);
    ts_gram<<<NBLK, BLOCK, 0, stream>>>(y_pred, y_true, ws);
    ts_final<<<1, 1024, 0, stream>>>(ws, out);
}

// Round 5
// 303.709 us; speedup vs baseline: 1.3714x; 1.3714x over previous
//
#include <hip/hip_runtime.h>

#define N_ROWS   1048576
#define T_COLS   32
#define NBLK     1024
#define BLOCK    256
#define ROWS_PER_WAVEPAIR 512          // rows per (block,sub) slice; 2 subs/block/matrix
#define CHUNKS   (ROWS_PER_WAVEPAIR / 16)   // 32 chunks of 16 rows
#define NWS      2080                   // 1024 Gt + 1024 Gp + 32 colsums

typedef _Float16 half8   __attribute__((ext_vector_type(8)));
typedef float    floatx16 __attribute__((ext_vector_type(16)));

// MFMA Gram: G = X^T X per 16-row chunk via mfma_f32_32x32x16_f16 with the
// SAME fragment fed as A and B (A/B lane maps are identical: dim=lane&31,
// k from lane>>5 + elem; any within-lane k-permutation cancels A vs B, and
// C/D transposition is harmless because G is symmetric).
// Loads: instr j reads X[chunk*16 + (lane>>5)*8 + j][lane&31] -> lanes 0-31
// and 32-63 each cover one dense 128-B line; 8 independent dwords per chunk
// per wave (16 lines in flight with unroll 2), no LDS, no barriers in loop.
// Block = 4 waves: wv>>1 = matrix (0=y_true,1=y_pred), wv&1 = row-sub.
__global__ __launch_bounds__(256, 4) void ts_gram(const float* __restrict__ y_pred,
                                                  const float* __restrict__ y_true,
                                                  float* __restrict__ ws) {
    __shared__ float s_red[NWS];

    const int tid  = threadIdx.x;
    const int wv   = tid >> 6;
    const int mtx  = wv >> 1;          // 0 = y_true, 1 = y_pred
    const int sub  = wv & 1;
    const int lane = tid & 63;
    const int half = lane >> 5;        // k-half within chunk
    const int col  = lane & 31;

    const float* src = (mtx == 0) ? y_true : y_pred;
    const size_t row0 = ((size_t)blockIdx.x * 2 + sub) * ROWS_PER_WAVEPAIR;
    // float index of this lane's first element: row (row0 + half*8), column col
    const float* p = src + row0 * T_COLS + (size_t)half * 8 * T_COLS + col;

    floatx16 acc = {};
    float lsum = 0.0f;

    #pragma unroll 2
    for (int c = 0; c < CHUNKS; ++c) {
        const float* cp = p + (size_t)c * 16 * T_COLS;
        float v[8];
        #pragma unroll
        for (int j = 0; j < 8; ++j) v[j] = cp[j * T_COLS];   // 8 indep dwords, 2 lines each
        half8 h;
        #pragma unroll
        for (int j = 0; j < 8; ++j) h[j] = (_Float16)v[j];
        if (mtx == 0) {                 // wave-uniform: colsum in fp32
            #pragma unroll
            for (int j = 0; j < 8; ++j) lsum += v[j];
        }
        acc = __builtin_amdgcn_mfma_f32_32x32x16_f16(h, h, acc, 0, 0, 0);
    }

    // ---- block reduction ----
    for (int i = tid; i < NWS; i += BLOCK) s_red[i] = 0.0f;
    __syncthreads();
    // C/D layout (m74/m101, dtype-independent): col=lane&31,
    // row=(reg&3)+8*(reg>>2)+4*(lane>>5). 2-way collisions (sub 0/1).
    #pragma unroll
    for (int r = 0; r < 16; ++r) {
        int row = (r & 3) + 8 * (r >> 2) + 4 * half;
        atomicAdd(&s_red[mtx * 1024 + row * 32 + col], acc[r]);
    }
    if (mtx == 0) atomicAdd(&s_red[2048 + col], lsum);   // 4-way collisions
    __syncthreads();
    for (int i = tid; i < NWS; i += BLOCK) atomicAdd(&ws[i], s_red[i]);
}

__global__ __launch_bounds__(1024) void ts_final(const float* __restrict__ w,
                                                 float* __restrict__ out) {
    __shared__ float s_S[32], s_nx[32], s_pn[32];
    __shared__ float s_red[16];
    const int tid = threadIdx.x;
    const float invN = 1.0f / (float)N_ROWS;

    if (tid < 32) {
        float S = w[2048 + tid];
        s_S[tid] = S;
        float d = w[tid * 32 + tid] - S * S * invN;   // centered diag
        s_nx[tid] = sqrtf(d);
        s_pn[tid] = sqrtf(w[1024 + tid * 33]);
    }
    __syncthreads();

    const int j = tid >> 5, k = tid & 31;
    float contrib = 0.0f;
    if (j >= 1 && k > j) {
        float gc  = w[j * 32 + k] - s_S[j] * s_S[k] * invN;
        float pcc = gc / (s_nx[j] * s_nx[k]);
        float cs  = w[1024 + j * 32 + k] / fmaxf(s_pn[j] * s_pn[k], 1e-8f);
        if (pcc >= 0.0f) contrib = 1.0f - cs;
    }
    #pragma unroll
    for (int off = 32; off > 0; off >>= 1) contrib += __shfl_down(contrib, off);
    if ((tid & 63) == 0) s_red[tid >> 6] = contrib;
    __syncthreads();
    if (tid == 0) {
        float tot = 0.0f;
        #pragma unroll
        for (int i = 0; i < 16; ++i) tot += s_red[i];
        out[0] = tot * (1.0f / 465.0f);   // c = (T-1)(T-2)/2
    }
}

extern "C" void kernel_launch(void* const* d_in, const int* in_sizes, int n_in,
                              void* d_out, int out_size, void* d_ws, size_t ws_size,
                              hipStream_t stream) {
    const float* y_pred = (const float*)d_in[0];
    const float* y_true = (const float*)d_in[1];
    float* out = (float*)d_out;
    float* ws  = (float*)d_ws;

    hipMemsetAsync(ws, 0, NWS * sizeof(float), stream);
    ts_gram<<<NBLK, BLOCK, 0, stream>>>(y_pred, y_true, ws);
    ts_final<<<1, 1024, 0, stream>>>(ws, out);
}